// Round 4
// 5657.022 us; speedup vs baseline: 1.1775x; 1.1775x over previous
//
#include <hip/hip_runtime.h>
#include <math.h>

typedef unsigned short ushort_t;
typedef unsigned long long u64;
typedef __attribute__((ext_vector_type(4))) float f32x4;
typedef __attribute__((ext_vector_type(8))) short s16x8;

// ---- workspace layout (bytes) ----
// xW   : [512][64][4096] bf16 (permuted gate cols, time-major)  268,435,456
// xb   : [64][512][1024] bf16                                    67,108,864
// wxp  : [4096][1024] bf16 (permuted rows, Wx part)               8,388,608
// whp  : [64][4][32][64][8] bf16 (per-block B-fragment order)     8,388,608
// bp   : [4096] f32 (permuted bias)                                  16,384
// hbuf : [2][64][1024] bf16                                         262,144
// cnt  : [2048] int  flag block (layout below)                        8,192
#define XW_OFF   0UL
#define XB_OFF   268435456UL
#define WXP_OFF  335544320UL
#define WHP_OFF  343932928UL
#define BP_OFF   352321536UL
#define HBUF_OFF 352337920UL
#define CNT_OFF  352600064UL

// cnt[] int layout:
//   [0]        init arrival counter
//   [1]        XCD presence bitmask
//   [2..9]     minbid per XCD (init 0x7FFFFFFF)
//   [16..527]  arrive[t]  (blocks that finished stores for step t)
//   [528..1039] done[t]   (XCD leaders that flushed L2 for step t)

__device__ __forceinline__ ushort_t f2bf(float f) {
  unsigned u = __builtin_bit_cast(unsigned, f);
  unsigned r = u + 0x7FFFu + ((u >> 16) & 1u);
  return (ushort_t)(r >> 16);
}
__device__ __forceinline__ float bf2f(ushort_t h) {
  unsigned u = ((unsigned)h) << 16;
  return __builtin_bit_cast(float, u);
}
__device__ __forceinline__ float sigm(float x) { return 1.f / (1.f + __expf(-x)); }
__device__ __forceinline__ float tanh_f(float x) {
  float t = __expf(-2.f * fabsf(x));
  float r = (1.f - t) / (1.f + t);
  return x >= 0.f ? r : -r;
}
// plain (cached) global->LDS, phase1 only (aux=0, proven in round 0)
__device__ __forceinline__ void gload_lds16(const void* g, void* l) {
  __builtin_amdgcn_global_load_lds(
      (const __attribute__((address_space(1))) unsigned int*)g,
      (__attribute__((address_space(3))) unsigned int*)l, 16, 0, 0);
}

// ------------------- prep: x fp32 -> bf16 -------------------
__global__ __launch_bounds__(256) void convert_x(const float* __restrict__ x,
                                                 ushort_t* __restrict__ xb) {
  long gid = (long)blockIdx.x * 256 + threadIdx.x;   // 4,194,304 threads x 8 elems
  const float4* x4 = (const float4*)x;
  float4 f0 = x4[gid * 2];
  float4 f1 = x4[gid * 2 + 1];
  s16x8 o;
  o[0] = (short)f2bf(f0.x); o[1] = (short)f2bf(f0.y);
  o[2] = (short)f2bf(f0.z); o[3] = (short)f2bf(f0.w);
  o[4] = (short)f2bf(f1.x); o[5] = (short)f2bf(f1.y);
  o[6] = (short)f2bf(f1.z); o[7] = (short)f2bf(f1.w);
  ((s16x8*)xb)[gid] = o;
}

// ------------------- prep: pack W / bias, zero h & counters -------------------
// permutation: block kb owns h-cols [kb*16, kb*16+16); block-local col c in [0,64):
//   gate g = c&3, local col jj = c>>2, original W row G = g*1024 + kb*16 + jj
__global__ __launch_bounds__(256) void prep_pack(const float* __restrict__ W,
                                                 const float* __restrict__ bias,
                                                 ushort_t* __restrict__ wxp,
                                                 ushort_t* __restrict__ whp,
                                                 float* __restrict__ bp,
                                                 ushort_t* __restrict__ hbuf,
                                                 int* __restrict__ cnt) {
  long gid = (long)blockIdx.x * 256 + threadIdx.x;
  if (gid < 524288) {                    // whp fragments: [kb][w][kc][l][8]
    int l = gid & 63, kc = (int)((gid >> 6) & 31), w = (int)((gid >> 11) & 3);
    int kb = (int)(gid >> 13);
    int li = l & 15, quad = l >> 4;
    int colb = w * 16 + li;
    int G = (colb & 3) * 1024 + kb * 16 + (colb >> 2);
    int kk = kc * 32 + quad * 8;
    const float* src = W + (long)G * 2048 + 1024 + kk;
    ushort_t* dst = whp + gid * 8;
#pragma unroll
    for (int j = 0; j < 8; ++j) dst[j] = f2bf(src[j]);
  } else if (gid < 1048576) {            // wxp: [R][k8*8..]
    long id = gid - 524288;
    int k8 = (int)(id & 127);
    int R = (int)(id >> 7);
    int c = R & 63, kb = R >> 6;
    int G = (c & 3) * 1024 + kb * 16 + (c >> 2);
    const float* src = W + (long)G * 2048 + k8 * 8;
    ushort_t* dst = wxp + (long)R * 1024 + k8 * 8;
#pragma unroll
    for (int j = 0; j < 8; ++j) dst[j] = f2bf(src[j]);
  } else if (gid < 1048576 + 4096) {     // permuted bias
    int R = (int)(gid - 1048576);
    int c = R & 63, kb = R >> 6;
    int G = (c & 3) * 1024 + kb * 16 + (c >> 2);
    bp[R] = bias[G];
  } else if (gid < 1048576 + 4096 + 8192) {  // zero hbuf[0]
    long id = gid - 1048576 - 4096;
    s16x8 z = {0, 0, 0, 0, 0, 0, 0, 0};
    ((s16x8*)hbuf)[id] = z;
  } else if (gid < 1048576 + 4096 + 8192 + 2048) {  // flag block
    int ci = (int)(gid - 1048576 - 4096 - 8192);
    cnt[ci] = (ci >= 2 && ci < 10) ? 0x7FFFFFFF : 0;   // minbid slots = +inf
  }
}

// ------------------- phase 1: xW = x @ Wx^T + b  (bf16 MFMA, 128x128 tile) ----
__global__ __launch_bounds__(256) void lstm_phase1(const ushort_t* __restrict__ xb,
                                                   const ushort_t* __restrict__ wxp,
                                                   const float* __restrict__ bp,
                                                   ushort_t* __restrict__ xw) {
  __shared__ ushort_t As[16 * 512];  // 16KB: [c=mt*2+kcl][lane][8], fragment order
  __shared__ ushort_t Bs[16 * 512];
  int bid = blockIdx.x;
  int nt = bid & 31, mtb = bid >> 5;
  int n0 = nt * 128;
  int t0 = mtb * 2;
  int tid = threadIdx.x, w = tid >> 6, l = tid & 63;
  int quad = l >> 4, li = l & 15;
  int mh = w & 1, nh = w >> 1;
  f32x4 acc[4][4] = {};

  for (int k0 = 0; k0 < 1024; k0 += 64) {
    __syncthreads();
#pragma unroll
    for (int i = 0; i < 4; ++i) {
      int c = w * 4 + i;
      int mt = c >> 1, kcl = c & 1;
      int r = mt * 16 + li;
      int tt = t0 + (r >> 6), bb = r & 63;
      gload_lds16(xb + (long)(bb * 512 + tt) * 1024 + k0 + kcl * 32 + quad * 8,
                  &As[c * 512]);
      int rn = n0 + mt * 16 + li;
      gload_lds16(wxp + (long)rn * 1024 + k0 + kcl * 32 + quad * 8, &Bs[c * 512]);
    }
    __syncthreads();
#pragma unroll
    for (int kcl = 0; kcl < 2; ++kcl) {
      s16x8 av[4], bv[4];
#pragma unroll
      for (int i = 0; i < 4; ++i)
        av[i] = *(const s16x8*)&As[((mh * 4 + i) * 2 + kcl) * 512 + l * 8];
#pragma unroll
      for (int j = 0; j < 4; ++j)
        bv[j] = *(const s16x8*)&Bs[((nh * 4 + j) * 2 + kcl) * 512 + l * 8];
#pragma unroll
      for (int i = 0; i < 4; ++i)
#pragma unroll
        for (int j = 0; j < 4; ++j)
          acc[i][j] =
              __builtin_amdgcn_mfma_f32_16x16x32_bf16(av[i], bv[j], acc[i][j], 0, 0, 0);
    }
  }
  // epilogue: + bias, store bf16 to xw[t*64+b][R]
#pragma unroll
  for (int j = 0; j < 4; ++j) {
    float bj = bp[n0 + nh * 64 + j * 16 + li];
#pragma unroll
    for (int i = 0; i < 4; ++i) {
#pragma unroll
      for (int r = 0; r < 4; ++r) {
        int lr = mh * 64 + i * 16 + quad * 4 + r;
        long off = ((long)mtb * 128 + lr) * 4096 + (n0 + nh * 64 + j * 16 + li);
        xw[off] = f2bf(acc[i][j][r] + bj);
      }
    }
  }
}

// ------------------- phase 2: persistent recurrent scan -------------------
// 256 blocks: group gr = bid>>6 (16 batch rows), slice kb = bid&63 (16 h-cols).
//
// Sync protocol v5 — leader-per-XCD maintenance, proven instruction classes only:
//  * h stores: PLAIN (land in local XCD L2), then per-wave s_waitcnt vmcnt(0)
//    (round-0-proven asm) + barrier.
//  * tid==0: RELAXED fetch_add arrive[t] (MALL RMW — proven class).
//  * ONE leader per XCD (elected once: s_getreg XCC_ID + atomicMin of bid):
//    spins arrive[t]==256, then RELEASE fetch_add done[t] -> ONE buffer_wbl2
//    per XCD per step (8 total, vs 256 in round 0) pushing all co-XCD h
//    stores to the MALL.
//  * everyone spins done[t]==NX (NX = popcount of XCD presence mask).
//  * consumers read h with RELAXED AGENT atomic u64 loads -> sc1, bypass
//    stale L1/L2, read the MALL. ZERO buffer_inv per step (round 0: 256).
//    Round-0's spin loop proved this load class is cross-XCD coherent.
//  * ALL spins guarded at 4096 polls (~1.3ms): any protocol bug terminates
//    fast with wrong results (diagnosable) — no hang, no harness timeout.
__global__ __launch_bounds__(256) void lstm_phase2(const ushort_t* __restrict__ xw,
                                                   const ushort_t* __restrict__ whp,
                                                   ushort_t* __restrict__ hbuf,
                                                   float* __restrict__ out,
                                                   int* __restrict__ counters) {
  __shared__ ushort_t Aimg[32 * 512];  // 32KB h fragment image: [kc][lane][8]
  int bid = blockIdx.x;
  int gr = bid >> 6, kb = bid & 63;
  int tid = threadIdx.x, w = tid >> 6, l = tid & 63;
  int quad = l >> 4, li = l & 15;
  int colb = w * 16 + li;          // block-local gate col 0..63
  int gg = colb & 3;               // gate: 0=cand 1=f 2=u 3=o
  int jj = colb >> 2;              // local h col 0..15
  int colh = kb * 16 + jj;         // global h col

  int* initc   = counters + 0;
  int* presw   = counters + 1;
  int* minbid  = counters + 2;
  int* arrive  = counters + 16;
  int* done    = counters + 528;

  // ---- init: XCD discovery + leader election (once) ----
  int isleader = 0, nx = 8;
  if (tid == 0) {
    unsigned xcc;
    asm volatile("s_getreg_b32 %0, hwreg(HW_REG_XCC_ID)" : "=s"(xcc));
    xcc &= 7u;
    __hip_atomic_fetch_or((unsigned*)presw, 1u << xcc, __ATOMIC_RELAXED,
                          __HIP_MEMORY_SCOPE_AGENT);
    __hip_atomic_fetch_min(minbid + xcc, bid, __ATOMIC_RELAXED,
                           __HIP_MEMORY_SCOPE_AGENT);
    asm volatile("s_waitcnt vmcnt(0)" ::: "memory");  // or/min at MALL first
    __hip_atomic_fetch_add(initc, 1, __ATOMIC_RELAXED, __HIP_MEMORY_SCOPE_AGENT);
    int g = 0;
    while (__hip_atomic_load(initc, __ATOMIC_RELAXED, __HIP_MEMORY_SCOPE_AGENT) < 256) {
      __builtin_amdgcn_s_sleep(8);
      if (++g > (1 << 20)) break;
    }
    unsigned pres =
        __hip_atomic_load((unsigned*)presw, __ATOMIC_RELAXED, __HIP_MEMORY_SCOPE_AGENT);
    nx = __builtin_popcount(pres);
    if (nx < 1) nx = 1;
    int mb = __hip_atomic_load(minbid + xcc, __ATOMIC_RELAXED, __HIP_MEMORY_SCOPE_AGENT);
    isleader = (mb == bid);
  }
  __syncthreads();

  // B fragments -> registers (stay live across all 512 steps)
  s16x8 bfr[32];
  const ushort_t* wp = whp + (long)(kb * 4 + w) * 32 * 512 + l * 8;
#pragma unroll
  for (int kc = 0; kc < 32; ++kc) bfr[kc] = *(const s16x8*)(wp + kc * 512);

  float cst[4] = {0.f, 0.f, 0.f, 0.f};
  // prefetch xw[t=0]
  ushort_t pf[4];
#pragma unroll
  for (int r = 0; r < 4; ++r)
    pf[r] = xw[(long)(gr * 16 + quad * 4 + r) * 4096 + kb * 64 + colb];

  int base = l & ~3;

  for (int t = 0; t < 512; ++t) {
    int p = t & 1;
    // coherent h image load: RELAXED AGENT u64 atomic loads (sc1 -> MALL),
    // byte-for-byte the round-0 DMA source/dest mapping.
    const u64* hsrc64 = (const u64*)(hbuf + p * 65536 + gr * 16 * 1024);
    u64 hv[16];
#pragma unroll
    for (int ci = 0; ci < 8; ++ci) {
      int kc = w * 8 + ci;
      const u64* s = hsrc64 + li * 256 + kc * 8 + quad * 2;
      hv[2 * ci] = __hip_atomic_load(s, __ATOMIC_RELAXED, __HIP_MEMORY_SCOPE_AGENT);
      hv[2 * ci + 1] =
          __hip_atomic_load(s + 1, __ATOMIC_RELAXED, __HIP_MEMORY_SCOPE_AGENT);
    }
    f32x4 a0, a1, a2, a3;
#pragma unroll
    for (int r = 0; r < 4; ++r) a0[r] = bf2f(pf[r]);
    a1 = (f32x4)0.f; a2 = (f32x4)0.f; a3 = (f32x4)0.f;
    if (t < 511) {
#pragma unroll
      for (int r = 0; r < 4; ++r)
        pf[r] = xw[(long)((t + 1) * 64 + gr * 16 + quad * 4 + r) * 4096 + kb * 64 + colb];
    }
    // stage h image into LDS (plain ds_write; compiler inserts the vmcnt wait)
#pragma unroll
    for (int ci = 0; ci < 8; ++ci) {
      int kc = w * 8 + ci;
      u64* d = (u64*)&Aimg[kc * 512 + l * 8];
      d[0] = hv[2 * ci];
      d[1] = hv[2 * ci + 1];
    }
    __syncthreads();
#pragma unroll
    for (int kc = 0; kc < 32; ++kc) {
      s16x8 a = *(const s16x8*)&Aimg[kc * 512 + l * 8];
      switch (kc & 3) {
        case 0: a0 = __builtin_amdgcn_mfma_f32_16x16x32_bf16(a, bfr[kc], a0, 0, 0, 0); break;
        case 1: a1 = __builtin_amdgcn_mfma_f32_16x16x32_bf16(a, bfr[kc], a1, 0, 0, 0); break;
        case 2: a2 = __builtin_amdgcn_mfma_f32_16x16x32_bf16(a, bfr[kc], a2, 0, 0, 0); break;
        default: a3 = __builtin_amdgcn_mfma_f32_16x16x32_bf16(a, bfr[kc], a3, 0, 0, 0); break;
      }
    }
    f32x4 pre4 = (a0 + a1) + (a2 + a3);

    float hn[4], cn[4];
#pragma unroll
    for (int r = 0; r < 4; ++r) {
      float pre = pre4[r];
      float candp = __shfl(pre, base + 0, 64);
      float fp_ = __shfl(pre, base + 1, 64);
      float up = __shfl(pre, base + 2, 64);
      float op = __shfl(pre, base + 3, 64);
      float c_ = sigm(up) * tanh_f(candp) + sigm(fp_) * cst[r];
      cst[r] = c_;
      cn[r] = c_;
      hn[r] = sigm(op) * tanh_f(c_);
    }
    // h stores: PLAIN (local L2); leader's wbl2 pushes them to the MALL.
    ushort_t* hdst = hbuf + (p ^ 1) * 65536;
    if (gg == 0) {
#pragma unroll
      for (int r = 0; r < 4; ++r) {
        int b = gr * 16 + quad * 4 + r;
        hdst[b * 1024 + colh] = f2bf(hn[r]);
        out[((long)b * 512 + t) * 1024 + colh] = hn[r];
        if (t == 511) {
          out[33554432 + b * 1024 + colh] = hn[r];
          out[33619968 + b * 1024 + colh] = cn[r];
        }
      }
    }
    // per-wave: h stores ack'd by L2 before signaling arrival
    asm volatile("s_waitcnt vmcnt(0)" ::: "memory");
    __syncthreads();
    if (tid == 0) {
      __hip_atomic_fetch_add(arrive + t, 1, __ATOMIC_RELAXED, __HIP_MEMORY_SCOPE_AGENT);
      if (isleader) {
        int g = 0;
        while (__hip_atomic_load(arrive + t, __ATOMIC_RELAXED,
                                 __HIP_MEMORY_SCOPE_AGENT) < 256) {
          __builtin_amdgcn_s_sleep(1);
          if (++g > 4096) break;
        }
        // RELEASE RMW: buffer_wbl2 (this XCD only — 8/step total) + MALL add
        __hip_atomic_fetch_add(done + t, 1, __ATOMIC_RELEASE, __HIP_MEMORY_SCOPE_AGENT);
      }
      int g = 0;
      while (__hip_atomic_load(done + t, __ATOMIC_RELAXED, __HIP_MEMORY_SCOPE_AGENT) < nx) {
        __builtin_amdgcn_s_sleep(1);
        if (++g > 4096) break;
      }
      // no ACQUIRE / buffer_inv: next step's h loads are sc1 atomic loads
    }
    __syncthreads();
  }
}

extern "C" void kernel_launch(void* const* d_in, const int* in_sizes, int n_in,
                              void* d_out, int out_size, void* d_ws, size_t ws_size,
                              hipStream_t stream) {
  const float* x = (const float*)d_in[0];
  const float* W = (const float*)d_in[1];
  const float* b = (const float*)d_in[2];
  float* out = (float*)d_out;
  char* ws = (char*)d_ws;
  ushort_t* xw = (ushort_t*)(ws + XW_OFF);
  ushort_t* xb = (ushort_t*)(ws + XB_OFF);
  ushort_t* wxp = (ushort_t*)(ws + WXP_OFF);
  ushort_t* whp = (ushort_t*)(ws + WHP_OFF);
  float* bp = (float*)(ws + BP_OFF);
  ushort_t* hbuf = (ushort_t*)(ws + HBUF_OFF);
  int* cnt = (int*)(ws + CNT_OFF);

  convert_x<<<16384, 256, 0, stream>>>(x, xb);
  prep_pack<<<4152, 256, 0, stream>>>(W, b, wxp, whp, bp, hbuf, cnt);
  lstm_phase1<<<8192, 256, 0, stream>>>(xb, wxp, bp, xw);
  lstm_phase2<<<256, 256, 0, stream>>>(xw, whp, hbuf, out, cnt);
}

// Round 5
// 4920.382 us; speedup vs baseline: 1.3538x; 1.1497x over previous
//
#include <hip/hip_runtime.h>
#include <math.h>

typedef unsigned short ushort_t;
typedef unsigned long long u64;
typedef __attribute__((ext_vector_type(4))) float f32x4;
typedef __attribute__((ext_vector_type(8))) short s16x8;

// ---- workspace layout (bytes) ----
// xW   : [512][64][4096] bf16 (permuted gate cols, time-major)  268,435,456
// xb   : [64][512][1024] bf16                                    67,108,864
// wxp  : [4096][1024] bf16 (permuted rows, Wx part)               8,388,608
// whp  : [64][4][32][64][8] bf16 (per-block B-fragment order)     8,388,608
// bp   : [4096] f32 (permuted bias)                                  16,384
// hbuf : [2][64][1024] bf16                                         262,144
// cnt  : [2048] int  (flags: [gr*64 + kb], monotone step counters)    8,192
#define XW_OFF   0UL
#define XB_OFF   268435456UL
#define WXP_OFF  335544320UL
#define WHP_OFF  343932928UL
#define BP_OFF   352321536UL
#define HBUF_OFF 352337920UL
#define CNT_OFF  352600064UL

__device__ __forceinline__ ushort_t f2bf(float f) {
  unsigned u = __builtin_bit_cast(unsigned, f);
  unsigned r = u + 0x7FFFu + ((u >> 16) & 1u);
  return (ushort_t)(r >> 16);
}
__device__ __forceinline__ float bf2f(ushort_t h) {
  unsigned u = ((unsigned)h) << 16;
  return __builtin_bit_cast(float, u);
}
__device__ __forceinline__ float sigm(float x) { return 1.f / (1.f + __expf(-x)); }
__device__ __forceinline__ float tanh_f(float x) {
  float t = __expf(-2.f * fabsf(x));
  float r = (1.f - t) / (1.f + t);
  return x >= 0.f ? r : -r;
}
// plain (cached) global->LDS, phase1 only (aux=0, proven)
__device__ __forceinline__ void gload_lds16(const void* g, void* l) {
  __builtin_amdgcn_global_load_lds(
      (const __attribute__((address_space(1))) unsigned int*)g,
      (__attribute__((address_space(3))) unsigned int*)l, 16, 0, 0);
}

// ------------------- prep: x fp32 -> bf16 -------------------
__global__ __launch_bounds__(256) void convert_x(const float* __restrict__ x,
                                                 ushort_t* __restrict__ xb) {
  long gid = (long)blockIdx.x * 256 + threadIdx.x;   // 4,194,304 threads x 8 elems
  const float4* x4 = (const float4*)x;
  float4 f0 = x4[gid * 2];
  float4 f1 = x4[gid * 2 + 1];
  s16x8 o;
  o[0] = (short)f2bf(f0.x); o[1] = (short)f2bf(f0.y);
  o[2] = (short)f2bf(f0.z); o[3] = (short)f2bf(f0.w);
  o[4] = (short)f2bf(f1.x); o[5] = (short)f2bf(f1.y);
  o[6] = (short)f2bf(f1.z); o[7] = (short)f2bf(f1.w);
  ((s16x8*)xb)[gid] = o;
}

// ------------------- prep: pack W / bias, zero h & counters -------------------
// permutation: block kb owns h-cols [kb*16, kb*16+16); block-local col c in [0,64):
//   gate g = c&3, local col jj = c>>2, original W row G = g*1024 + kb*16 + jj
__global__ __launch_bounds__(256) void prep_pack(const float* __restrict__ W,
                                                 const float* __restrict__ bias,
                                                 ushort_t* __restrict__ wxp,
                                                 ushort_t* __restrict__ whp,
                                                 float* __restrict__ bp,
                                                 ushort_t* __restrict__ hbuf,
                                                 int* __restrict__ cnt) {
  long gid = (long)blockIdx.x * 256 + threadIdx.x;
  if (gid < 524288) {                    // whp fragments: [kb][w][kc][l][8]
    int l = gid & 63, kc = (int)((gid >> 6) & 31), w = (int)((gid >> 11) & 3);
    int kb = (int)(gid >> 13);
    int li = l & 15, quad = l >> 4;
    int colb = w * 16 + li;
    int G = (colb & 3) * 1024 + kb * 16 + (colb >> 2);
    int kk = kc * 32 + quad * 8;
    const float* src = W + (long)G * 2048 + 1024 + kk;
    ushort_t* dst = whp + gid * 8;
#pragma unroll
    for (int j = 0; j < 8; ++j) dst[j] = f2bf(src[j]);
  } else if (gid < 1048576) {            // wxp: [R][k8*8..]
    long id = gid - 524288;
    int k8 = (int)(id & 127);
    int R = (int)(id >> 7);
    int c = R & 63, kb = R >> 6;
    int G = (c & 3) * 1024 + kb * 16 + (c >> 2);
    const float* src = W + (long)G * 2048 + k8 * 8;
    ushort_t* dst = wxp + (long)R * 1024 + k8 * 8;
#pragma unroll
    for (int j = 0; j < 8; ++j) dst[j] = f2bf(src[j]);
  } else if (gid < 1048576 + 4096) {     // permuted bias
    int R = (int)(gid - 1048576);
    int c = R & 63, kb = R >> 6;
    int G = (c & 3) * 1024 + kb * 16 + (c >> 2);
    bp[R] = bias[G];
  } else if (gid < 1048576 + 4096 + 8192) {  // zero hbuf[0]
    long id = gid - 1048576 - 4096;
    s16x8 z = {0, 0, 0, 0, 0, 0, 0, 0};
    ((s16x8*)hbuf)[id] = z;
  } else if (gid < 1048576 + 4096 + 8192 + 2048) {  // zero flags
    cnt[gid - 1048576 - 4096 - 8192] = 0;
  }
  // NOTE: end-of-kernel implicit system release flushes these plain stores to
  // the MALL, so phase2's sc1 (L2-bypassing) reads see them.
}

// ------------------- phase 1: xW = x @ Wx^T + b  (bf16 MFMA, 128x128 tile) ----
__global__ __launch_bounds__(256) void lstm_phase1(const ushort_t* __restrict__ xb,
                                                   const ushort_t* __restrict__ wxp,
                                                   const float* __restrict__ bp,
                                                   ushort_t* __restrict__ xw) {
  __shared__ ushort_t As[16 * 512];  // 16KB: [c=mt*2+kcl][lane][8], fragment order
  __shared__ ushort_t Bs[16 * 512];
  int bid = blockIdx.x;
  int nt = bid & 31, mtb = bid >> 5;
  int n0 = nt * 128;
  int t0 = mtb * 2;
  int tid = threadIdx.x, w = tid >> 6, l = tid & 63;
  int quad = l >> 4, li = l & 15;
  int mh = w & 1, nh = w >> 1;
  f32x4 acc[4][4] = {};

  for (int k0 = 0; k0 < 1024; k0 += 64) {
    __syncthreads();
#pragma unroll
    for (int i = 0; i < 4; ++i) {
      int c = w * 4 + i;
      int mt = c >> 1, kcl = c & 1;
      int r = mt * 16 + li;
      int tt = t0 + (r >> 6), bb = r & 63;
      gload_lds16(xb + (long)(bb * 512 + tt) * 1024 + k0 + kcl * 32 + quad * 8,
                  &As[c * 512]);
      int rn = n0 + mt * 16 + li;
      gload_lds16(wxp + (long)rn * 1024 + k0 + kcl * 32 + quad * 8, &Bs[c * 512]);
    }
    __syncthreads();
#pragma unroll
    for (int kcl = 0; kcl < 2; ++kcl) {
      s16x8 av[4], bv[4];
#pragma unroll
      for (int i = 0; i < 4; ++i)
        av[i] = *(const s16x8*)&As[((mh * 4 + i) * 2 + kcl) * 512 + l * 8];
#pragma unroll
      for (int j = 0; j < 4; ++j)
        bv[j] = *(const s16x8*)&Bs[((nh * 4 + j) * 2 + kcl) * 512 + l * 8];
#pragma unroll
      for (int i = 0; i < 4; ++i)
#pragma unroll
        for (int j = 0; j < 4; ++j)
          acc[i][j] =
              __builtin_amdgcn_mfma_f32_16x16x32_bf16(av[i], bv[j], acc[i][j], 0, 0, 0);
    }
  }
  // epilogue: + bias, store bf16 to xw[t*64+b][R]
#pragma unroll
  for (int j = 0; j < 4; ++j) {
    float bj = bp[n0 + nh * 64 + j * 16 + li];
#pragma unroll
    for (int i = 0; i < 4; ++i) {
#pragma unroll
      for (int r = 0; r < 4; ++r) {
        int lr = mh * 64 + i * 16 + quad * 4 + r;
        long off = ((long)mtb * 128 + lr) * 4096 + (n0 + nh * 64 + j * 16 + li);
        xw[off] = f2bf(acc[i][j][r] + bj);
      }
    }
  }
}

// ------------------- phase 2: persistent recurrent scan -------------------
// 256 blocks: group gr = bid>>6 (16 batch rows), slice kb = bid&63 (16 h-cols).
//
// Sync protocol v6 — single-stage, contention-free, per-group, zero maintenance:
//  * h stores: __hip_atomic_store RELAXED/AGENT (sc1 -> ack at MALL). Round 4
//    proved RELAXED/AGENT sc1 LOADS coherently read MALL data; stores are the
//    matching compiler-generated class. NO wbl2, NO inv, NO leaders.
//  * per-wave s_waitcnt vmcnt(0) (= release for sc1 stores) -> barrier ->
//    tid0 sc1-stores flag[gr][kb] = t+1 (own slot: no RMW, no contention).
//  * out[] plain stores AFTER the flag -> drain overlaps the next poll.
//  * consumer poll: lane l sc1-loads flag[gr][l]; __all(f >= t) -> ONE MALL
//    round trip checks the whole 64-block group barrier. All waves poll
//    independently (no extra __syncthreads on the poll path).
//  * flags are monotone (t+1): no reset, double-buffered hbuf gives WAR safety
//    (a block can lead its group by at most 1 step).
//  * polls guarded at 1024 iters: any protocol bug terminates fast with wrong
//    results (diagnosable) — no hang, no harness timeout.
__global__ __launch_bounds__(256) void lstm_phase2(const ushort_t* __restrict__ xw,
                                                   const ushort_t* __restrict__ whp,
                                                   ushort_t* __restrict__ hbuf,
                                                   float* __restrict__ out,
                                                   int* __restrict__ counters) {
  __shared__ ushort_t Aimg[32 * 512];  // 32KB h fragment image: [kc][lane][8]
  int bid = blockIdx.x;
  int gr = bid >> 6, kb = bid & 63;
  int tid = threadIdx.x, w = tid >> 6, l = tid & 63;
  int quad = l >> 4, li = l & 15;
  int colb = w * 16 + li;          // block-local gate col 0..63
  int gg = colb & 3;               // gate: 0=cand 1=f 2=u 3=o
  int jj = colb >> 2;              // local h col 0..15
  int colh = kb * 16 + jj;         // global h col

  int* flags = counters + gr * 64;   // one int per block of this group

  // B fragments -> registers (stay live across all 512 steps)
  s16x8 bfr[32];
  const ushort_t* wp = whp + (long)(kb * 4 + w) * 32 * 512 + l * 8;
#pragma unroll
  for (int kc = 0; kc < 32; ++kc) bfr[kc] = *(const s16x8*)(wp + kc * 512);

  float cst[4] = {0.f, 0.f, 0.f, 0.f};
  // prefetch xw[t=0]
  ushort_t pf[4];
#pragma unroll
  for (int r = 0; r < 4; ++r)
    pf[r] = xw[(long)(gr * 16 + quad * 4 + r) * 4096 + kb * 64 + colb];

  int base = l & ~3;

  for (int t = 0; t < 512; ++t) {
    int p = t & 1;
    // ---- wave-parallel group barrier: wait until all 64 blocks flagged t ----
    if (t > 0) {
      int g = 0;
      for (;;) {
        int f = __hip_atomic_load(flags + l, __ATOMIC_RELAXED, __HIP_MEMORY_SCOPE_AGENT);
        if (__all(f >= t)) break;
        if (++g > 1024) break;   // safety valve: terminate, fail visibly
      }
    }
    // ---- coherent h image load: RELAXED/AGENT u64 loads (sc1 -> MALL) ----
    const u64* hsrc64 = (const u64*)(hbuf + p * 65536 + gr * 16 * 1024);
    u64 hv[16];
#pragma unroll
    for (int ci = 0; ci < 8; ++ci) {
      int kc = w * 8 + ci;
      const u64* s = hsrc64 + li * 256 + kc * 8 + quad * 2;
      hv[2 * ci] = __hip_atomic_load(s, __ATOMIC_RELAXED, __HIP_MEMORY_SCOPE_AGENT);
      hv[2 * ci + 1] =
          __hip_atomic_load(s + 1, __ATOMIC_RELAXED, __HIP_MEMORY_SCOPE_AGENT);
    }
    f32x4 a0, a1, a2, a3;
#pragma unroll
    for (int r = 0; r < 4; ++r) a0[r] = bf2f(pf[r]);
    a1 = (f32x4)0.f; a2 = (f32x4)0.f; a3 = (f32x4)0.f;
    if (t < 511) {
#pragma unroll
      for (int r = 0; r < 4; ++r)
        pf[r] = xw[(long)((t + 1) * 64 + gr * 16 + quad * 4 + r) * 4096 + kb * 64 + colb];
    }
    // stage h image into LDS (plain ds_write; compiler inserts the vmcnt wait)
#pragma unroll
    for (int ci = 0; ci < 8; ++ci) {
      int kc = w * 8 + ci;
      u64* d = (u64*)&Aimg[kc * 512 + l * 8];
      d[0] = hv[2 * ci];
      d[1] = hv[2 * ci + 1];
    }
    __syncthreads();
#pragma unroll
    for (int kc = 0; kc < 32; ++kc) {
      s16x8 a = *(const s16x8*)&Aimg[kc * 512 + l * 8];
      switch (kc & 3) {
        case 0: a0 = __builtin_amdgcn_mfma_f32_16x16x32_bf16(a, bfr[kc], a0, 0, 0, 0); break;
        case 1: a1 = __builtin_amdgcn_mfma_f32_16x16x32_bf16(a, bfr[kc], a1, 0, 0, 0); break;
        case 2: a2 = __builtin_amdgcn_mfma_f32_16x16x32_bf16(a, bfr[kc], a2, 0, 0, 0); break;
        default: a3 = __builtin_amdgcn_mfma_f32_16x16x32_bf16(a, bfr[kc], a3, 0, 0, 0); break;
      }
    }
    f32x4 pre4 = (a0 + a1) + (a2 + a3);

    float hn[4], cn[4];
#pragma unroll
    for (int r = 0; r < 4; ++r) {
      float pre = pre4[r];
      float candp = __shfl(pre, base + 0, 64);
      float fp_ = __shfl(pre, base + 1, 64);
      float up = __shfl(pre, base + 2, 64);
      float op = __shfl(pre, base + 3, 64);
      float c_ = sigm(up) * tanh_f(candp) + sigm(fp_) * cst[r];
      cst[r] = c_;
      cn[r] = c_;
      hn[r] = sigm(op) * tanh_f(c_);
    }
    // ---- h stores: sc1 packed dwords (ack at MALL) ----
    ushort_t* hdst = hbuf + (p ^ 1) * 65536;
    if (gg == 0) {
#pragma unroll
      for (int r = 0; r < 4; ++r) {
        int b = gr * 16 + quad * 4 + r;
        unsigned hb = (unsigned)f2bf(hn[r]);
        unsigned ob = __shfl_xor(hb, 4, 64);   // partner lane li^4 = colh+1
        if ((li & 7) == 0) {
          unsigned packed = hb | (ob << 16);
          __hip_atomic_store((unsigned*)&hdst[b * 1024 + colh], packed,
                             __ATOMIC_RELAXED, __HIP_MEMORY_SCOPE_AGENT);
        }
      }
    }
    // per-wave: sc1 h stores ack'd at the MALL before the barrier (= release)
    asm volatile("s_waitcnt vmcnt(0)" ::: "memory");
    __syncthreads();
    if (tid == 0)
      __hip_atomic_store(flags + kb, t + 1, __ATOMIC_RELAXED, __HIP_MEMORY_SCOPE_AGENT);
    // out[] plain stores AFTER the flag: drain overlaps the next poll
    if (gg == 0) {
#pragma unroll
      for (int r = 0; r < 4; ++r) {
        int b = gr * 16 + quad * 4 + r;
        out[((long)b * 512 + t) * 1024 + colh] = hn[r];
        if (t == 511) {
          out[33554432 + b * 1024 + colh] = hn[r];
          out[33619968 + b * 1024 + colh] = cn[r];
        }
      }
    }
  }
}

extern "C" void kernel_launch(void* const* d_in, const int* in_sizes, int n_in,
                              void* d_out, int out_size, void* d_ws, size_t ws_size,
                              hipStream_t stream) {
  const float* x = (const float*)d_in[0];
  const float* W = (const float*)d_in[1];
  const float* b = (const float*)d_in[2];
  float* out = (float*)d_out;
  char* ws = (char*)d_ws;
  ushort_t* xw = (ushort_t*)(ws + XW_OFF);
  ushort_t* xb = (ushort_t*)(ws + XB_OFF);
  ushort_t* wxp = (ushort_t*)(ws + WXP_OFF);
  ushort_t* whp = (ushort_t*)(ws + WHP_OFF);
  float* bp = (float*)(ws + BP_OFF);
  ushort_t* hbuf = (ushort_t*)(ws + HBUF_OFF);
  int* cnt = (int*)(ws + CNT_OFF);

  convert_x<<<16384, 256, 0, stream>>>(x, xb);
  prep_pack<<<4152, 256, 0, stream>>>(W, b, wxp, whp, bp, hbuf, cnt);
  lstm_phase1<<<8192, 256, 0, stream>>>(xb, wxp, bp, xw);
  lstm_phase2<<<256, 256, 0, stream>>>(xw, whp, hbuf, out, cnt);
}

// Round 6
// 4566.121 us; speedup vs baseline: 1.4588x; 1.0776x over previous
//
#include <hip/hip_runtime.h>
#include <math.h>

typedef unsigned short ushort_t;
typedef unsigned long long u64;
typedef __attribute__((ext_vector_type(4))) float f32x4;
typedef __attribute__((ext_vector_type(8))) short s16x8;
typedef __attribute__((ext_vector_type(4))) int s32x4;

// ---- workspace layout (bytes) ----
// xW   : [512][64][4096] bf16 (permuted gate cols, time-major)  268,435,456
// xb   : [64][512][1024] bf16                                    67,108,864
// wxp  : [4096][1024] bf16 (permuted rows, Wx part)               8,388,608
// whp  : [64][4][32][64][8] bf16 (per-block B-fragment order)     8,388,608
// bp   : [4096] f32 (permuted bias)                                  16,384
// hbuf : [2][64][1024] bf16                                         262,144
// cnt  : [2048] int  (flags: [gr][kb][w] = gr*256 + kb*4 + w)         8,192
#define XW_OFF   0UL
#define XB_OFF   268435456UL
#define WXP_OFF  335544320UL
#define WHP_OFF  343932928UL
#define BP_OFF   352321536UL
#define HBUF_OFF 352337920UL
#define CNT_OFF  352600064UL

__device__ __forceinline__ ushort_t f2bf(float f) {
  unsigned u = __builtin_bit_cast(unsigned, f);
  unsigned r = u + 0x7FFFu + ((u >> 16) & 1u);
  return (ushort_t)(r >> 16);
}
__device__ __forceinline__ float bf2f(ushort_t h) {
  unsigned u = ((unsigned)h) << 16;
  return __builtin_bit_cast(float, u);
}
__device__ __forceinline__ float sigm(float x) { return 1.f / (1.f + __expf(-x)); }
__device__ __forceinline__ float tanh_f(float x) {
  float t = __expf(-2.f * fabsf(x));
  float r = (1.f - t) / (1.f + t);
  return x >= 0.f ? r : -r;
}
// plain (cached) global->LDS, phase1 only (aux=0, proven)
__device__ __forceinline__ void gload_lds16(const void* g, void* l) {
  __builtin_amdgcn_global_load_lds(
      (const __attribute__((address_space(1))) unsigned int*)g,
      (__attribute__((address_space(3))) unsigned int*)l, 16, 0, 0);
}
// 16B device-coherent load: same sc1 CPol LLVM emits for agent atomics,
// just the dwordx4 width. NO waitcnt inside — caller drains vmcnt.
__device__ __forceinline__ void gload16_cc(const void* p, s32x4& v) {
  asm volatile("global_load_dwordx4 %0, %1, off sc1"
               : "=v"(v) : "v"(p) : "memory");
}

// ------------------- prep: x fp32 -> bf16 -------------------
__global__ __launch_bounds__(256) void convert_x(const float* __restrict__ x,
                                                 ushort_t* __restrict__ xb) {
  long gid = (long)blockIdx.x * 256 + threadIdx.x;   // 4,194,304 threads x 8 elems
  const float4* x4 = (const float4*)x;
  float4 f0 = x4[gid * 2];
  float4 f1 = x4[gid * 2 + 1];
  s16x8 o;
  o[0] = (short)f2bf(f0.x); o[1] = (short)f2bf(f0.y);
  o[2] = (short)f2bf(f0.z); o[3] = (short)f2bf(f0.w);
  o[4] = (short)f2bf(f1.x); o[5] = (short)f2bf(f1.y);
  o[6] = (short)f2bf(f1.z); o[7] = (short)f2bf(f1.w);
  ((s16x8*)xb)[gid] = o;
}

// ------------------- prep: pack W / bias, zero h & counters -------------------
// permutation: block kb owns h-cols [kb*16, kb*16+16); block-local col c in [0,64):
//   gate g = c&3, local col jj = c>>2, original W row G = g*1024 + kb*16 + jj
__global__ __launch_bounds__(256) void prep_pack(const float* __restrict__ W,
                                                 const float* __restrict__ bias,
                                                 ushort_t* __restrict__ wxp,
                                                 ushort_t* __restrict__ whp,
                                                 float* __restrict__ bp,
                                                 ushort_t* __restrict__ hbuf,
                                                 int* __restrict__ cnt) {
  long gid = (long)blockIdx.x * 256 + threadIdx.x;
  if (gid < 524288) {                    // whp fragments: [kb][w][kc][l][8]
    int l = gid & 63, kc = (int)((gid >> 6) & 31), w = (int)((gid >> 11) & 3);
    int kb = (int)(gid >> 13);
    int li = l & 15, quad = l >> 4;
    int colb = w * 16 + li;
    int G = (colb & 3) * 1024 + kb * 16 + (colb >> 2);
    int kk = kc * 32 + quad * 8;
    const float* src = W + (long)G * 2048 + 1024 + kk;
    ushort_t* dst = whp + gid * 8;
#pragma unroll
    for (int j = 0; j < 8; ++j) dst[j] = f2bf(src[j]);
  } else if (gid < 1048576) {            // wxp: [R][k8*8..]
    long id = gid - 524288;
    int k8 = (int)(id & 127);
    int R = (int)(id >> 7);
    int c = R & 63, kb = R >> 6;
    int G = (c & 3) * 1024 + kb * 16 + (c >> 2);
    const float* src = W + (long)G * 2048 + k8 * 8;
    ushort_t* dst = wxp + (long)R * 1024 + k8 * 8;
#pragma unroll
    for (int j = 0; j < 8; ++j) dst[j] = f2bf(src[j]);
  } else if (gid < 1048576 + 4096) {     // permuted bias
    int R = (int)(gid - 1048576);
    int c = R & 63, kb = R >> 6;
    int G = (c & 3) * 1024 + kb * 16 + (c >> 2);
    bp[R] = bias[G];
  } else if (gid < 1048576 + 4096 + 8192) {  // zero hbuf[0]
    long id = gid - 1048576 - 4096;
    s16x8 z = {0, 0, 0, 0, 0, 0, 0, 0};
    ((s16x8*)hbuf)[id] = z;
  } else if (gid < 1048576 + 4096 + 8192 + 2048) {  // zero flags
    cnt[gid - 1048576 - 4096 - 8192] = 0;
  }
  // NOTE: end-of-kernel implicit system release flushes these plain stores to
  // the MALL, so phase2's sc1 (L2-bypassing) reads see them.
}

// ------------------- phase 1: xW = x @ Wx^T + b  (bf16 MFMA, 128x128 tile) ----
__global__ __launch_bounds__(256) void lstm_phase1(const ushort_t* __restrict__ xb,
                                                   const ushort_t* __restrict__ wxp,
                                                   const float* __restrict__ bp,
                                                   ushort_t* __restrict__ xw) {
  __shared__ ushort_t As[16 * 512];  // 16KB: [c=mt*2+kcl][lane][8], fragment order
  __shared__ ushort_t Bs[16 * 512];
  int bid = blockIdx.x;
  int nt = bid & 31, mtb = bid >> 5;
  int n0 = nt * 128;
  int t0 = mtb * 2;
  int tid = threadIdx.x, w = tid >> 6, l = tid & 63;
  int quad = l >> 4, li = l & 15;
  int mh = w & 1, nh = w >> 1;
  f32x4 acc[4][4] = {};

  for (int k0 = 0; k0 < 1024; k0 += 64) {
    __syncthreads();
#pragma unroll
    for (int i = 0; i < 4; ++i) {
      int c = w * 4 + i;
      int mt = c >> 1, kcl = c & 1;
      int r = mt * 16 + li;
      int tt = t0 + (r >> 6), bb = r & 63;
      gload_lds16(xb + (long)(bb * 512 + tt) * 1024 + k0 + kcl * 32 + quad * 8,
                  &As[c * 512]);
      int rn = n0 + mt * 16 + li;
      gload_lds16(wxp + (long)rn * 1024 + k0 + kcl * 32 + quad * 8, &Bs[c * 512]);
    }
    __syncthreads();
#pragma unroll
    for (int kcl = 0; kcl < 2; ++kcl) {
      s16x8 av[4], bv[4];
#pragma unroll
      for (int i = 0; i < 4; ++i)
        av[i] = *(const s16x8*)&As[((mh * 4 + i) * 2 + kcl) * 512 + l * 8];
#pragma unroll
      for (int j = 0; j < 4; ++j)
        bv[j] = *(const s16x8*)&Bs[((nh * 4 + j) * 2 + kcl) * 512 + l * 8];
#pragma unroll
      for (int i = 0; i < 4; ++i)
#pragma unroll
        for (int j = 0; j < 4; ++j)
          acc[i][j] =
              __builtin_amdgcn_mfma_f32_16x16x32_bf16(av[i], bv[j], acc[i][j], 0, 0, 0);
    }
  }
  // epilogue: + bias, store bf16 to xw[t*64+b][R]
#pragma unroll
  for (int j = 0; j < 4; ++j) {
    float bj = bp[n0 + nh * 64 + j * 16 + li];
#pragma unroll
    for (int i = 0; i < 4; ++i) {
#pragma unroll
      for (int r = 0; r < 4; ++r) {
        int lr = mh * 64 + i * 16 + quad * 4 + r;
        long off = ((long)mtb * 128 + lr) * 4096 + (n0 + nh * 64 + j * 16 + li);
        xw[off] = f2bf(acc[i][j][r] + bj);
      }
    }
  }
}

// ------------------- phase 2: persistent recurrent scan -------------------
// 256 blocks: group gr = bid>>6 (16 batch rows), slice kb = bid&63 (16 h-cols).
//
// Sync protocol v7 — v6 with coherent-transaction count minimized:
//  * h image read: 8 x 16B global_load_dwordx4 sc1 per thread (was 16 x 8B
//    atomic loads): HALF the MALL transactions. Explicit vmcnt(0) +
//    sched_barrier before the dependent ds_writes (compiler doesn't track
//    asm loads).
//  * h stores: one 8B u64 relaxed-agent atomic per (wave,row) — 16/wave
//    (was 32 x 4B/wave): half the transactions, contiguous 8B (less
//    write-through partial-line amplification seen in round 5's WRITE_SIZE).
//  * PER-WAVE flags [gr][kb][w]: each wave flags right after ITS vmcnt(0) —
//    no producer __syncthreads, no tid0 serialization. Consumer: lane l polls
//    flags[4l..4l+3] via ONE 16B sc1 load; __all() over 256 flags in one RTT.
//    The poll doubles as the inter-iteration barrier: a wave passes poll t
//    only after every wave of every block flagged t, i.e. finished reading
//    h(t-1) — protects both Aimg and the double-buffered hbuf (max skew 1).
//  * polls guarded at 1024 iters: bugs terminate fast + visibly, never hang.
__global__ __launch_bounds__(256) void lstm_phase2(const ushort_t* __restrict__ xw,
                                                   const ushort_t* __restrict__ whp,
                                                   ushort_t* __restrict__ hbuf,
                                                   float* __restrict__ out,
                                                   int* __restrict__ counters) {
  __shared__ ushort_t Aimg[32 * 512];  // 32KB h fragment image: [kc][lane][8]
  int bid = blockIdx.x;
  int gr = bid >> 6, kb = bid & 63;
  int tid = threadIdx.x, w = tid >> 6, l = tid & 63;
  int quad = l >> 4, li = l & 15;
  int colb = w * 16 + li;          // block-local gate col 0..63
  int gg = colb & 3;               // gate: 0=cand 1=f 2=u 3=o
  int jj = colb >> 2;              // local h col 0..15
  int colh = kb * 16 + jj;         // global h col

  int* flags = counters + gr * 256;   // [kb][w]

  // B fragments -> registers (stay live across all 512 steps)
  s16x8 bfr[32];
  const ushort_t* wp = whp + (long)(kb * 4 + w) * 32 * 512 + l * 8;
#pragma unroll
  for (int kc = 0; kc < 32; ++kc) bfr[kc] = *(const s16x8*)(wp + kc * 512);

  float cst[4] = {0.f, 0.f, 0.f, 0.f};
  // prefetch xw[t=0]
  ushort_t pf[4];
#pragma unroll
  for (int r = 0; r < 4; ++r)
    pf[r] = xw[(long)(gr * 16 + quad * 4 + r) * 4096 + kb * 64 + colb];

  int base = l & ~3;

  for (int t = 0; t < 512; ++t) {
    int p = t & 1;
    // ---- wave-parallel group barrier: one 16B sc1 load scans 256 flags ----
    if (t > 0) {
      const void* fl4 = (const void*)(flags + l * 4);
      int g = 0;
      for (;;) {
        s32x4 f;
        asm volatile("global_load_dwordx4 %0, %1, off sc1\n\ts_waitcnt vmcnt(0)"
                     : "=v"(f) : "v"(fl4) : "memory");
        if (__all(f[0] >= t && f[1] >= t && f[2] >= t && f[3] >= t)) break;
        if (++g > 1024) break;   // safety valve: terminate, fail visibly
      }
    }
    // ---- coherent h image load: 8 x 16B sc1 loads into registers ----
    const char* hsrc = (const char*)hbuf + (long)p * 131072 + (long)gr * 32768;
    s32x4 hv[8];
#pragma unroll
    for (int ci = 0; ci < 8; ++ci) {
      int kc = w * 8 + ci;
      gload16_cc(hsrc + li * 2048 + kc * 64 + quad * 16, hv[ci]);
    }
    f32x4 a0, a1, a2, a3;
#pragma unroll
    for (int r = 0; r < 4; ++r) a0[r] = bf2f(pf[r]);
    a1 = (f32x4)0.f; a2 = (f32x4)0.f; a3 = (f32x4)0.f;
    if (t < 511) {
#pragma unroll
      for (int r = 0; r < 4; ++r)
        pf[r] = xw[(long)((t + 1) * 64 + gr * 16 + quad * 4 + r) * 4096 + kb * 64 + colb];
    }
    // drain asm loads (and incidental prefetch) before using hv in ds_write
    asm volatile("s_waitcnt vmcnt(0)" ::: "memory");
    __builtin_amdgcn_sched_barrier(0);
#pragma unroll
    for (int ci = 0; ci < 8; ++ci) {
      int kc = w * 8 + ci;
      *(s32x4*)&Aimg[kc * 512 + l * 8] = hv[ci];
    }
    __syncthreads();
#pragma unroll
    for (int kc = 0; kc < 32; ++kc) {
      s16x8 a = *(const s16x8*)&Aimg[kc * 512 + l * 8];
      switch (kc & 3) {
        case 0: a0 = __builtin_amdgcn_mfma_f32_16x16x32_bf16(a, bfr[kc], a0, 0, 0, 0); break;
        case 1: a1 = __builtin_amdgcn_mfma_f32_16x16x32_bf16(a, bfr[kc], a1, 0, 0, 0); break;
        case 2: a2 = __builtin_amdgcn_mfma_f32_16x16x32_bf16(a, bfr[kc], a2, 0, 0, 0); break;
        default: a3 = __builtin_amdgcn_mfma_f32_16x16x32_bf16(a, bfr[kc], a3, 0, 0, 0); break;
      }
    }
    f32x4 pre4 = (a0 + a1) + (a2 + a3);

    float hn[4], cn[4];
#pragma unroll
    for (int r = 0; r < 4; ++r) {
      float pre = pre4[r];
      float candp = __shfl(pre, base + 0, 64);
      float fp_ = __shfl(pre, base + 1, 64);
      float up = __shfl(pre, base + 2, 64);
      float op = __shfl(pre, base + 3, 64);
      float c_ = sigm(up) * tanh_f(candp) + sigm(fp_) * cst[r];
      cst[r] = c_;
      cn[r] = c_;
      hn[r] = sigm(op) * tanh_f(c_);
    }
    // ---- h stores: one 8B sc1 atomic per (wave,row); cols w*4..w*4+3 ----
    // hn[r] is identical across each 4-lane cluster; cluster k (li=4k..4k+3)
    // holds col w*4+k. Lane li==0 gathers the 4 cluster values per row.
    ushort_t* hdst = hbuf + (p ^ 1) * 65536;
#pragma unroll
    for (int r = 0; r < 4; ++r) {
      unsigned hb = (unsigned)f2bf(hn[r]);
      unsigned c0 = __shfl(hb, base - (l & 3) - (li & 12) + 0, 64);   // li=0 cluster
      unsigned c1 = __shfl(hb, (quad << 4) + 4, 64);
      unsigned c2 = __shfl(hb, (quad << 4) + 8, 64);
      unsigned c3 = __shfl(hb, (quad << 4) + 12, 64);
      c0 = __shfl(hb, (quad << 4) + 0, 64);
      if (li == 0) {
        int b = gr * 16 + quad * 4 + r;
        u64 packed = (u64)c0 | ((u64)c1 << 16) | ((u64)c2 << 32) | ((u64)c3 << 48);
        __hip_atomic_store((u64*)&hdst[b * 1024 + kb * 16 + w * 4], packed,
                           __ATOMIC_RELAXED, __HIP_MEMORY_SCOPE_AGENT);
      }
    }
    // per-wave: sc1 h stores ack'd at the MALL, then THIS wave's flag
    asm volatile("s_waitcnt vmcnt(0)" ::: "memory");
    if (l == 0)
      __hip_atomic_store(flags + kb * 4 + w, t + 1, __ATOMIC_RELAXED,
                         __HIP_MEMORY_SCOPE_AGENT);
    // out[] plain stores AFTER the flag: drain overlaps the next poll
    if (gg == 0) {
#pragma unroll
      for (int r = 0; r < 4; ++r) {
        int b = gr * 16 + quad * 4 + r;
        out[((long)b * 512 + t) * 1024 + colh] = hn[r];
        if (t == 511) {
          out[33554432 + b * 1024 + colh] = hn[r];
          out[33619968 + b * 1024 + colh] = cn[r];
        }
      }
    }
  }
}

extern "C" void kernel_launch(void* const* d_in, const int* in_sizes, int n_in,
                              void* d_out, int out_size, void* d_ws, size_t ws_size,
                              hipStream_t stream) {
  const float* x = (const float*)d_in[0];
  const float* W = (const float*)d_in[1];
  const float* b = (const float*)d_in[2];
  float* out = (float*)d_out;
  char* ws = (char*)d_ws;
  ushort_t* xw = (ushort_t*)(ws + XW_OFF);
  ushort_t* xb = (ushort_t*)(ws + XB_OFF);
  ushort_t* wxp = (ushort_t*)(ws + WXP_OFF);
  ushort_t* whp = (ushort_t*)(ws + WHP_OFF);
  float* bp = (float*)(ws + BP_OFF);
  ushort_t* hbuf = (ushort_t*)(ws + HBUF_OFF);
  int* cnt = (int*)(ws + CNT_OFF);

  convert_x<<<16384, 256, 0, stream>>>(x, xb);
  prep_pack<<<4152, 256, 0, stream>>>(W, b, wxp, whp, bp, hbuf, cnt);
  lstm_phase1<<<8192, 256, 0, stream>>>(xb, wxp, bp, xw);
  lstm_phase2<<<256, 256, 0, stream>>>(xw, whp, hbuf, out, cnt);
}

// Round 11
// 4462.453 us; speedup vs baseline: 1.4927x; 1.0232x over previous
//
#include <hip/hip_runtime.h>
#include <math.h>

typedef unsigned short ushort_t;
typedef unsigned long long u64;
typedef __attribute__((ext_vector_type(4))) float f32x4;
typedef __attribute__((ext_vector_type(8))) short s16x8;
typedef __attribute__((ext_vector_type(4))) int s32x4;

// ---- workspace layout (bytes) ----
// xW   : [512][64][4096] bf16 (permuted gate cols, time-major)  268,435,456
// xb   : [64][512][1024] bf16                                    67,108,864
//        (first 512KB reused as hbuf2 AFTER phase1 — xb is dead then)
// wxp  : [4096][1024] bf16 (permuted rows, Wx part)               8,388,608
// whp  : [64][4][32][64][8] bf16 (per-slice B-fragment order)     8,388,608
// bp   : [4096] f32 (permuted bias)                                  16,384
// hbuf : legacy region (unused by v12)                              262,144
// cnt  : legacy region (unused by v12)                                8,192
// hbuf2: [2][64][512] u64 tagged chunks {h0,h1,tag} @ XB_OFF        524,288
#define XW_OFF   0UL
#define XB_OFF   268435456UL
#define WXP_OFF  335544320UL
#define WHP_OFF  343932928UL
#define BP_OFF   352321536UL
#define HBUF_OFF 352337920UL
#define CNT_OFF  352600064UL

__device__ __forceinline__ ushort_t f2bf(float f) {
  unsigned u = __builtin_bit_cast(unsigned, f);
  unsigned r = u + 0x7FFFu + ((u >> 16) & 1u);
  return (ushort_t)(r >> 16);
}
__device__ __forceinline__ float bf2f(ushort_t h) {
  unsigned u = ((unsigned)h) << 16;
  return __builtin_bit_cast(float, u);
}
__device__ __forceinline__ float sigm(float x) { return 1.f / (1.f + __expf(-x)); }
__device__ __forceinline__ float tanh_f(float x) {
  float t = __expf(-2.f * fabsf(x));
  float r = (1.f - t) / (1.f + t);
  return x >= 0.f ? r : -r;
}
// plain (cached) global->LDS, phase1 only (aux=0, proven)
__device__ __forceinline__ void gload_lds16(const void* g, void* l) {
  __builtin_amdgcn_global_load_lds(
      (const __attribute__((address_space(1))) unsigned int*)g,
      (__attribute__((address_space(3))) unsigned int*)l, 16, 0, 0);
}
// 16B device-coherent load (sc1 -> MALL), proven in rounds 5-6.
__device__ __forceinline__ void gload16_cc(const void* p, s32x4& v) {
  asm volatile("global_load_dwordx4 %0, %1, off sc1"
               : "=v"(v) : "v"(p) : "memory");
}

// ------------------- prep: x fp32 -> bf16 -------------------
__global__ __launch_bounds__(256) void convert_x(const float* __restrict__ x,
                                                 ushort_t* __restrict__ xb) {
  long gid = (long)blockIdx.x * 256 + threadIdx.x;   // 4,194,304 threads x 8 elems
  const float4* x4 = (const float4*)x;
  float4 f0 = x4[gid * 2];
  float4 f1 = x4[gid * 2 + 1];
  s16x8 o;
  o[0] = (short)f2bf(f0.x); o[1] = (short)f2bf(f0.y);
  o[2] = (short)f2bf(f0.z); o[3] = (short)f2bf(f0.w);
  o[4] = (short)f2bf(f1.x); o[5] = (short)f2bf(f1.y);
  o[6] = (short)f2bf(f1.z); o[7] = (short)f2bf(f1.w);
  ((s16x8*)xb)[gid] = o;
}

// ------------------- prep: pack W / bias (legacy zeroing harmless) ----------
__global__ __launch_bounds__(256) void prep_pack(const float* __restrict__ W,
                                                 const float* __restrict__ bias,
                                                 ushort_t* __restrict__ wxp,
                                                 ushort_t* __restrict__ whp,
                                                 float* __restrict__ bp,
                                                 ushort_t* __restrict__ hbuf,
                                                 int* __restrict__ cnt) {
  long gid = (long)blockIdx.x * 256 + threadIdx.x;
  if (gid < 524288) {                    // whp fragments: [kb][w][kc][l][8]
    int l = gid & 63, kc = (int)((gid >> 6) & 31), w = (int)((gid >> 11) & 3);
    int kb = (int)(gid >> 13);
    int li = l & 15, quad = l >> 4;
    int colb = w * 16 + li;
    int G = (colb & 3) * 1024 + kb * 16 + (colb >> 2);
    int kk = kc * 32 + quad * 8;
    const float* src = W + (long)G * 2048 + 1024 + kk;
    ushort_t* dst = whp + gid * 8;
#pragma unroll
    for (int j = 0; j < 8; ++j) dst[j] = f2bf(src[j]);
  } else if (gid < 1048576) {            // wxp: [R][k8*8..]
    long id = gid - 524288;
    int k8 = (int)(id & 127);
    int R = (int)(id >> 7);
    int c = R & 63, kb = R >> 6;
    int G = (c & 3) * 1024 + kb * 16 + (c >> 2);
    const float* src = W + (long)G * 2048 + k8 * 8;
    ushort_t* dst = wxp + (long)R * 1024 + k8 * 8;
#pragma unroll
    for (int j = 0; j < 8; ++j) dst[j] = f2bf(src[j]);
  } else if (gid < 1048576 + 4096) {     // permuted bias
    int R = (int)(gid - 1048576);
    int c = R & 63, kb = R >> 6;
    int G = (c & 3) * 1024 + kb * 16 + (c >> 2);
    bp[R] = bias[G];
  } else if (gid < 1048576 + 4096 + 8192) {  // legacy hbuf zero (unused)
    long id = gid - 1048576 - 4096;
    s16x8 z = {0, 0, 0, 0, 0, 0, 0, 0};
    ((s16x8*)hbuf)[id] = z;
  } else if (gid < 1048576 + 4096 + 8192 + 2048) {  // legacy cnt zero (unused)
    cnt[gid - 1048576 - 4096 - 8192] = 0;
  }
}

// ------------------- zero tagged h buffer (runs AFTER phase1: xb is dead) ---
__global__ __launch_bounds__(256) void zero_hbuf2(s32x4* __restrict__ hb) {
  long gid = (long)blockIdx.x * 256 + threadIdx.x;   // 32768 x 16B = 512KB
  s32x4 z = {0, 0, 0, 0};
  hb[gid] = z;
}

// ------------------- phase 1: xW = x @ Wx^T + b  (bf16 MFMA, 128x128 tile) ----
__global__ __launch_bounds__(256) void lstm_phase1(const ushort_t* __restrict__ xb,
                                                   const ushort_t* __restrict__ wxp,
                                                   const float* __restrict__ bp,
                                                   ushort_t* __restrict__ xw) {
  __shared__ ushort_t As[16 * 512];  // 16KB: [c=mt*2+kcl][lane][8], fragment order
  __shared__ ushort_t Bs[16 * 512];
  int bid = blockIdx.x;
  int nt = bid & 31, mtb = bid >> 5;
  int n0 = nt * 128;
  int t0 = mtb * 2;
  int tid = threadIdx.x, w = tid >> 6, l = tid & 63;
  int quad = l >> 4, li = l & 15;
  int mh = w & 1, nh = w >> 1;
  f32x4 acc[4][4] = {};

  for (int k0 = 0; k0 < 1024; k0 += 64) {
    __syncthreads();
#pragma unroll
    for (int i = 0; i < 4; ++i) {
      int c = w * 4 + i;
      int mt = c >> 1, kcl = c & 1;
      int r = mt * 16 + li;
      int tt = t0 + (r >> 6), bb = r & 63;
      gload_lds16(xb + (long)(bb * 512 + tt) * 1024 + k0 + kcl * 32 + quad * 8,
                  &As[c * 512]);
      int rn = n0 + mt * 16 + li;
      gload_lds16(wxp + (long)rn * 1024 + k0 + kcl * 32 + quad * 8, &Bs[c * 512]);
    }
    __syncthreads();
#pragma unroll
    for (int kcl = 0; kcl < 2; ++kcl) {
      s16x8 av[4], bv[4];
#pragma unroll
      for (int i = 0; i < 4; ++i)
        av[i] = *(const s16x8*)&As[((mh * 4 + i) * 2 + kcl) * 512 + l * 8];
#pragma unroll
      for (int j = 0; j < 4; ++j)
        bv[j] = *(const s16x8*)&Bs[((nh * 4 + j) * 2 + kcl) * 512 + l * 8];
#pragma unroll
      for (int i = 0; i < 4; ++i)
#pragma unroll
        for (int j = 0; j < 4; ++j)
          acc[i][j] =
              __builtin_amdgcn_mfma_f32_16x16x32_bf16(av[i], bv[j], acc[i][j], 0, 0, 0);
    }
  }
  // epilogue: + bias, store bf16 to xw[t*64+b][R]
#pragma unroll
  for (int j = 0; j < 4; ++j) {
    float bj = bp[n0 + nh * 64 + j * 16 + li];
#pragma unroll
    for (int i = 0; i < 4; ++i) {
#pragma unroll
      for (int r = 0; r < 4; ++r) {
        int lr = mh * 64 + i * 16 + quad * 4 + r;
        long off = ((long)mtb * 128 + lr) * 4096 + (n0 + nh * 64 + j * 16 + li);
        xw[off] = f2bf(acc[i][j][r] + bj);
      }
    }
  }
}

// ------------------- phase 2: persistent recurrent scan -------------------
// v12 = v7's proven shape (256 blocks x 256 thr, sc1/MALL data path) with the
// sync folded INTO the data: each 8B hbuf2 chunk = {2 x bf16, 32-bit step tag}
// written by ONE relaxed-agent u64 store (atomic, proven class).
//   Consumers poll the chunks directly: 16 x dwordx4 sc1 loads, check all 32
//   embedded tags == t, retry. This removes from the critical path:
//   producer vmcnt(0) ack wait, the flag store, and the flag-poll RTT —
//   leaving one-way store flight + poll hit.
//   WAR safety (2 buffers, exact-tag check): producer P writes tag t+2 into
//   buffer p only after P's poll(t+1) saw EVERY slice's t+1 tags; a slice
//   publishes t+1 only after completing all its t-reads of buffer p. So
//   during any consumer's poll(t), buffer p holds only tags {t-2, t}.
//   Poll guarded (4096 retries): bugs terminate fast + visibly, never hang.
__global__ __launch_bounds__(256) void lstm_phase2(const ushort_t* __restrict__ xw,
                                                   const ushort_t* __restrict__ whp,
                                                   u64* __restrict__ hbuf2,
                                                   float* __restrict__ out) {
  __shared__ ushort_t Aimg[32 * 512];  // 32KB h fragment image: [kc][lane][8]
  int bid = blockIdx.x;
  int gr = bid >> 6, kb = bid & 63;
  int tid = threadIdx.x, w = tid >> 6, l = tid & 63;
  int quad = l >> 4, li = l & 15;
  int colb = w * 16 + li;          // block-local gate col 0..63
  int gg = colb & 3;               // gate: 0=cand 1=f 2=u 3=o
  int jj = colb >> 2;              // local h col 0..15
  int colh = kb * 16 + jj;         // global h col

  // B fragments -> registers (live across all 512 steps)
  s16x8 bfr[32];
  const ushort_t* wp = whp + (long)(kb * 4 + w) * 32 * 512 + l * 8;
#pragma unroll
  for (int kc = 0; kc < 32; ++kc) bfr[kc] = *(const s16x8*)(wp + kc * 512);

  float cst[4] = {0.f, 0.f, 0.f, 0.f};
  // prefetch xw[t=0]
  ushort_t pf[4];
#pragma unroll
  for (int r = 0; r < 4; ++r)
    pf[r] = xw[(long)(gr * 16 + quad * 4 + r) * 4096 + kb * 64 + colb];

  int base = l & ~3;

  for (int t = 0; t < 512; ++t) {
    int p = t & 1;
    // ---- self-validating h image: load chunk-pairs until all tags == t ----
    // row = gr*16 + li; chunk cp = kc*16 + quad*4 + {0..3}; each dwordx4
    // covers 2 chunks: lanes check hv[i][1] and hv[i][3] (the tags).
    const char* hb = (const char*)hbuf2 + (long)p * 262144 + (long)(gr * 16 + li) * 4096;
    s32x4 hv[16];
    {
      int g = 0;
      for (;;) {
#pragma unroll
        for (int ci = 0; ci < 8; ++ci) {
          int kc = w * 8 + ci;
          const char* a = hb + (kc * 16 + quad * 4) * 8;
          gload16_cc(a, hv[2 * ci]);
          gload16_cc(a + 16, hv[2 * ci + 1]);
        }
        asm volatile("s_waitcnt vmcnt(0)" ::: "memory");
        __builtin_amdgcn_sched_barrier(0);
        int ok = 1;
#pragma unroll
        for (int i = 0; i < 16; ++i) ok &= (hv[i][1] == t) & (hv[i][3] == t);
        if (__all(ok)) break;
        if (++g > 4096) break;   // safety valve: terminate, fail visibly
      }
    }
    // consume pf into acc, then issue NEXT prefetch early (hides HBM latency)
    f32x4 a0, a1, a2, a3;
#pragma unroll
    for (int r = 0; r < 4; ++r) a0[r] = bf2f(pf[r]);
    a1 = (f32x4)0.f; a2 = (f32x4)0.f; a3 = (f32x4)0.f;
    if (t < 511) {
#pragma unroll
      for (int r = 0; r < 4; ++r)
        pf[r] = xw[(long)((t + 1) * 64 + gr * 16 + quad * 4 + r) * 4096 + kb * 64 + colb];
    }
    // extract data dwords (lo of each chunk) -> Aimg fragments (v7 byte order)
#pragma unroll
    for (int ci = 0; ci < 8; ++ci) {
      int kc = w * 8 + ci;
      s32x4 d;
      d[0] = hv[2 * ci][0];
      d[1] = hv[2 * ci][2];
      d[2] = hv[2 * ci + 1][0];
      d[3] = hv[2 * ci + 1][2];
      *(s32x4*)&Aimg[kc * 512 + l * 8] = d;
    }
    __syncthreads();
#pragma unroll
    for (int kc = 0; kc < 32; ++kc) {
      s16x8 a = *(const s16x8*)&Aimg[kc * 512 + l * 8];
      switch (kc & 3) {
        case 0: a0 = __builtin_amdgcn_mfma_f32_16x16x32_bf16(a, bfr[kc], a0, 0, 0, 0); break;
        case 1: a1 = __builtin_amdgcn_mfma_f32_16x16x32_bf16(a, bfr[kc], a1, 0, 0, 0); break;
        case 2: a2 = __builtin_amdgcn_mfma_f32_16x16x32_bf16(a, bfr[kc], a2, 0, 0, 0); break;
        default: a3 = __builtin_amdgcn_mfma_f32_16x16x32_bf16(a, bfr[kc], a3, 0, 0, 0); break;
      }
    }
    f32x4 pre4 = (a0 + a1) + (a2 + a3);
    __syncthreads();   // all Aimg reads done before next iter's ds_writes

    float hn[4], cn[4];
#pragma unroll
    for (int r = 0; r < 4; ++r) {
      float pre = pre4[r];
      float candp = __shfl(pre, base + 0, 64);
      float fp_ = __shfl(pre, base + 1, 64);
      float up = __shfl(pre, base + 2, 64);
      float op = __shfl(pre, base + 3, 64);
      float c_ = sigm(up) * tanh_f(candp) + sigm(fp_) * cst[r];
      cst[r] = c_;
      cn[r] = c_;
      hn[r] = sigm(op) * tanh_f(c_);
    }
    // ---- tagged h stores: 2 x u64 {2 cols, tag=t+1} per (wave,row) ----
    u64* hd = hbuf2 + (long)(p ^ 1) * 32768;
    u64 tag = ((u64)(unsigned)(t + 1)) << 32;
#pragma unroll
    for (int r = 0; r < 4; ++r) {
      unsigned hb_ = (unsigned)f2bf(hn[r]);
      unsigned c0 = __shfl(hb_, (quad << 4) + 0, 64);
      unsigned c1 = __shfl(hb_, (quad << 4) + 4, 64);
      unsigned c2 = __shfl(hb_, (quad << 4) + 8, 64);
      unsigned c3 = __shfl(hb_, (quad << 4) + 12, 64);
      if (li == 0) {
        int b = gr * 16 + quad * 4 + r;
        u64 tA = (u64)c0 | ((u64)c1 << 16) | tag;
        u64 tB = (u64)c2 | ((u64)c3 << 16) | tag;
        __hip_atomic_store(hd + (long)b * 512 + kb * 8 + w * 2, tA,
                           __ATOMIC_RELAXED, __HIP_MEMORY_SCOPE_AGENT);
        __hip_atomic_store(hd + (long)b * 512 + kb * 8 + w * 2 + 1, tB,
                           __ATOMIC_RELAXED, __HIP_MEMORY_SCOPE_AGENT);
      }
    }
    // out[] plain stores last (off the critical path)
    if (gg == 0) {
#pragma unroll
      for (int r = 0; r < 4; ++r) {
        int b = gr * 16 + quad * 4 + r;
        out[((long)b * 512 + t) * 1024 + colh] = hn[r];
        if (t == 511) {
          out[33554432 + b * 1024 + colh] = hn[r];
          out[33619968 + b * 1024 + colh] = cn[r];
        }
      }
    }
  }
}

extern "C" void kernel_launch(void* const* d_in, const int* in_sizes, int n_in,
                              void* d_out, int out_size, void* d_ws, size_t ws_size,
                              hipStream_t stream) {
  const float* x = (const float*)d_in[0];
  const float* W = (const float*)d_in[1];
  const float* b = (const float*)d_in[2];
  float* out = (float*)d_out;
  char* ws = (char*)d_ws;
  ushort_t* xw = (ushort_t*)(ws + XW_OFF);
  ushort_t* xb = (ushort_t*)(ws + XB_OFF);
  ushort_t* wxp = (ushort_t*)(ws + WXP_OFF);
  ushort_t* whp = (ushort_t*)(ws + WHP_OFF);
  float* bp = (float*)(ws + BP_OFF);
  ushort_t* hbuf = (ushort_t*)(ws + HBUF_OFF);
  int* cnt = (int*)(ws + CNT_OFF);
  u64* hbuf2 = (u64*)(ws + XB_OFF);   // overlays dead xb after phase1

  convert_x<<<16384, 256, 0, stream>>>(x, xb);
  prep_pack<<<4152, 256, 0, stream>>>(W, b, wxp, whp, bp, hbuf, cnt);
  lstm_phase1<<<8192, 256, 0, stream>>>(xb, wxp, bp, xw);
  zero_hbuf2<<<128, 256, 0, stream>>>((s32x4*)hbuf2);
  lstm_phase2<<<256, 256, 0, stream>>>(xw, whp, hbuf2, out);
}